// Round 13
// baseline (7898.660 us; speedup 1.0000x reference)
//
#include <hip/hip_runtime.h>

typedef unsigned int u32;
typedef unsigned short u16;
typedef unsigned long long u64;
typedef _Float16 f16;
typedef __attribute__((ext_vector_type(4))) float f32x4;
typedef __attribute__((ext_vector_type(8))) _Float16 f16x8;
typedef __attribute__((ext_vector_type(4))) _Float16 f16x4;
typedef __attribute__((ext_vector_type(4))) u32 u32v4;

#define DEVI static __device__ __forceinline__

constexpr int B_ = 32, T_ = 2048, NS_ = 128, CD_ = 512, NM_ = 80;
constexpr int BT_ = B_ * T_;        // 65536

struct HL { f16 h, l; };
DEVI HL splitH(float f) {
  HL r;
  r.h = (f16)f;
  r.l = (f16)(f - (float)r.h);
  return r;
}
DEVI float h2f_lo(u32 u) { return (float)__builtin_bit_cast(f16, (u16)(u & 0xffffu)); }
DEVI float h2f_hi(u32 u) { return (float)__builtin_bit_cast(f16, (u16)(u >> 16)); }
DEVI u32 pack2h(float a, float b) {
  u16 x = __builtin_bit_cast(u16, (f16)a);
  u16 y = __builtin_bit_cast(u16, (f16)b);
  return (u32)x | ((u32)y << 16);
}
DEVI float sigm(float x) { return 1.f / (1.f + __expf(-x)); }
DEVI float tanh_(float x) {
  float e = __expf(2.f * x);
  return 1.f - 2.f / (e + 1.f);
}

// ---- compose conv(emb(.)): W2[o][kk*128+n] = sum_e emb[n][e]*cw[o][e][kk] --
__global__ __launch_bounds__(256) void k_compose(const float* __restrict__ emb,
                                                 const float* __restrict__ cw,
                                                 f16* __restrict__ WH,
                                                 f16* __restrict__ WL) {
  int idx = blockIdx.x * 256 + threadIdx.x;        // 512*384 = 196608
  int o = idx / 384, k = idx - o * 384;
  int kk = k >> 7, n = k & 127;
  const float* er = emb + n * 128;
  const float* wr = cw + (size_t)o * 384 + kk;     // stride 3 over e
  float a = 0.f;
  for (int e = 0; e < 128; ++e) a += er[e] * wr[e * 3];
  HL s = splitH(a);
  WH[(size_t)o * 384 + k] = s.h;
  WL[(size_t)o * 384 + k] = s.l;
}

__global__ __launch_bounds__(256) void k_packlin(const float* __restrict__ lw,
                                                 f16* __restrict__ LH,
                                                 f16* __restrict__ LL) {
  int i = blockIdx.x * 256 + threadIdx.x;          // 80*1024 = 81920
  HL s = splitH(lw[i]);
  LH[i] = s.h;
  LL[i] = s.l;
}

// ---- conv as GEMM (split-f16): Y[bt][o] = relu(Xrow(t..t+2) . Wc[o]) -------
__global__ __launch_bounds__(256) void k_conv(const float* __restrict__ x,
                                              const f16* __restrict__ WH,
                                              const f16* __restrict__ WL,
                                              f16* __restrict__ Y) {
  __shared__ f16 XsH[34][136];
  __shared__ f16 XsL[34][136];
  const int tid = threadIdx.x;
  const int b = blockIdx.x >> 6;
  const int t0 = (blockIdx.x & 63) * 32;
  const int n0 = blockIdx.y * 64;
  const int lane = tid & 63, wave = tid >> 6;
  const int n = lane & 15, klo = (lane >> 4) * 8;

  f16x8 bH[12], bL[12];
  {
    const size_t brow = (size_t)(n0 + wave * 16 + n) * 384 + klo;
#pragma unroll
    for (int kt = 0; kt < 12; ++kt) {
      bH[kt] = *(const f16x8*)(WH + brow + kt * 32);
      bL[kt] = *(const f16x8*)(WL + brow + kt * 32);
    }
  }
  for (int idx = tid; idx < 34 * 32; idx += 256) {
    int row = idx >> 5, q = idx & 31;
    int trow = t0 - 1 + row;
    f16x4 vh = {0, 0, 0, 0}, vl = {0, 0, 0, 0};
    if (trow >= 0 && trow < T_) {
      float4 v = *(const float4*)(x + ((size_t)b * T_ + trow) * NS_ + 4 * q);
      HL s0 = splitH(v.x), s1 = splitH(v.y), s2 = splitH(v.z), s3 = splitH(v.w);
      vh[0] = s0.h; vl[0] = s0.l;
      vh[1] = s1.h; vl[1] = s1.l;
      vh[2] = s2.h; vl[2] = s2.l;
      vh[3] = s3.h; vl[3] = s3.l;
    }
    *(f16x4*)&XsH[row][4 * q] = vh;
    *(f16x4*)&XsL[row][4 * q] = vl;
  }
  __syncthreads();

  f32x4 aH_[2] = {{0,0,0,0},{0,0,0,0}}, aM_[2] = {{0,0,0,0},{0,0,0,0}};
#pragma unroll
  for (int kt = 0; kt < 12; ++kt) {
    int kk = kt >> 2, i = (kt & 3) * 32 + klo;
#pragma unroll
    for (int m = 0; m < 2; ++m) {
      f16x8 ah = *(const f16x8*)&XsH[m * 16 + n + kk][i];
      f16x8 al = *(const f16x8*)&XsL[m * 16 + n + kk][i];
      aH_[m] = __builtin_amdgcn_mfma_f32_16x16x32_f16(ah, bH[kt], aH_[m], 0, 0, 0);
      aM_[m] = __builtin_amdgcn_mfma_f32_16x16x32_f16(ah, bL[kt], aM_[m], 0, 0, 0);
      aM_[m] = __builtin_amdgcn_mfma_f32_16x16x32_f16(al, bH[kt], aM_[m], 0, 0, 0);
    }
  }
  const int rq = (lane >> 4) * 4;
#pragma unroll
  for (int m = 0; m < 2; ++m)
#pragma unroll
    for (int q = 0; q < 4; ++q) {
      int rowg = blockIdx.x * 32 + m * 16 + rq + q;
      float v = aH_[m][q] + aM_[m][q];
      Y[(size_t)rowg * CD_ + n0 + wave * 16 + n] = (f16)(v > 0.f ? v : 0.f);
    }
}

// ---------------- BN stats / scale / apply ---------------------------------
__global__ __launch_bounds__(256) void k_bnstats(const f16* __restrict__ Y,
                                                 float* __restrict__ sums,
                                                 float* __restrict__ sumsq) {
  const u32* Y32 = (const u32*)Y;
  int r0 = blockIdx.x * 64;
  float a0 = 0, a1 = 0, q0 = 0, q1 = 0;
  for (int i = 0; i < 64; ++i) {
    u32 v = Y32[(size_t)(r0 + i) * 256 + threadIdx.x];
    float x0 = h2f_lo(v), x1 = h2f_hi(v);
    a0 += x0; a1 += x1; q0 += x0 * x0; q1 += x1 * x1;
  }
  int c = threadIdx.x * 2;
  atomicAdd(&sums[c], a0); atomicAdd(&sums[c + 1], a1);
  atomicAdd(&sumsq[c], q0); atomicAdd(&sumsq[c + 1], q1);
}

__global__ void k_bnscale(const float* __restrict__ sums, const float* __restrict__ sumsq,
                          const float* __restrict__ g, const float* __restrict__ be,
                          float* __restrict__ scl, float* __restrict__ shf) {
  int c = blockIdx.x * 256 + threadIdx.x;
  if (c < CD_) {
    float m = sums[c] * (1.f / 65536.f);
    float v = sumsq[c] * (1.f / 65536.f) - m * m;
    float s = g[c] * rsqrtf(v + 1e-5f);
    scl[c] = s; shf[c] = be[c] - m * s;
  }
}

__global__ __launch_bounds__(256) void k_bnapply(f16* __restrict__ Y,
                                                 const float* __restrict__ scl,
                                                 const float* __restrict__ shf) {
  const int total = BT_ * CD_ / 8;
  int idx0 = blockIdx.x * 256 + threadIdx.x;
  int c0 = (idx0 & 63) * 8;
  float sc[8], sh[8];
#pragma unroll
  for (int j = 0; j < 8; ++j) { sc[j] = scl[c0 + j]; sh[j] = shf[c0 + j]; }
  u32v4* Yv = (u32v4*)Y;
  for (int idx = idx0; idx < total; idx += 2048 * 256) {
    u32v4 v = Yv[idx], o;
#pragma unroll
    for (int j = 0; j < 4; ++j) {
      float lo = h2f_lo(v[j]) * sc[2 * j] + sh[2 * j];
      float hi = h2f_hi(v[j]) * sc[2 * j + 1] + sh[2 * j + 1];
      o[j] = pack2h(lo, hi);
    }
    Yv[idx] = o;
  }
}

// ---- poll helpers: issue 8 relaxed agent loads / validate+decode ----------
DEVI void poll_issue(const u64* p, u64 s[8]) {
#pragma unroll
  for (int q = 0; q < 4; ++q) {
    s[2 * q] = __hip_atomic_load(p + q * 8, __ATOMIC_RELAXED,
                                 __HIP_MEMORY_SCOPE_AGENT);
    s[2 * q + 1] = __hip_atomic_load(p + q * 8 + 1, __ATOMIC_RELAXED,
                                     __HIP_MEMORY_SCOPE_AGENT);
  }
}
DEVI u32 poll_check(const u64 s[8], u32v4 dec[4]) {
  u32 bad = 0;
#pragma unroll
  for (int q = 0; q < 4; ++q) {
    u32 w0 = (u32)s[2 * q], w1 = (u32)(s[2 * q] >> 32);
    u32 w2 = (u32)s[2 * q + 1], w3 = (u32)(s[2 * q + 1] >> 32);
    u32 d0 = w0 - 0x00010001u, d1 = w1 - 0x00010001u;
    u32 d2 = w2 - 0x00010001u, d3 = w3 - 0x00010001u;
    bad |= (d0 & ~w0 & 0x80008000u) | (d1 & ~w1 & 0x80008000u) |
           (d2 & ~w2 & 0x80008000u) | (d3 & ~w3 & 0x80008000u);
    dec[q][0] = d0; dec[q][1] = d1; dec[q][2] = d2; dec[q][3] = d3;
  }
  return bad;
}

// ---------------- persistent bidirectional LSTM (K-split waves) -------------
// 128 blocks x 256 thr, 4 groups (dir x batch-half) of 32 blocks; block owns
// 16 units. Wave = K-quarter (128 units), all 4 gates over its slice; each
// wave polls only its own slice (8 producer blocks) with a 2-deep pipelined
// poll (two sample sets in flight -> halves detect quantization), decodes in
// registers, feeds MFMA directly. IH MFMA runs BEFORE the poll (no h dep);
// x(s+1) prefetch issues before the poll so poll+HH+gates cover its latency.
// Parity-double-buffered partial LDS -> ONE barrier/step. h published as
// bits(f16)+1 into zeroed T-deep slots via relaxed agent stores (sc1); ALL
// hT readers (here and k_final) use the same agent-scope loads.
__global__ __launch_bounds__(256, 1) void k_lstm(
    const f16* __restrict__ Y, const float* __restrict__ w_ih_f,
    const float* __restrict__ w_hh_f, const float* __restrict__ b_f,
    const float* __restrict__ w_ih_b, const float* __restrict__ w_hh_b,
    const float* __restrict__ b_b, u16* __restrict__ hT) {
  __shared__ float g_lds[2][4][4][16][17];  // [parity][gate][wave][row][col]
  const int tid = threadIdx.x;
  const int lane = tid & 63, wv = tid >> 6;
  const int bid = blockIdx.x;
  const int g = bid >> 5;                          // group 0..3
  const int dir = g >> 1, bh = g & 1;
  const int u0 = (bid & 31) * 16;                  // hidden-unit base
  const int n = lane & 15;                         // batch row / unit col
  const int klo = (lane >> 4) * 8;
  const int kq = wv * 128 + klo;                   // wave K-slice + lane offset

  const float* Wih = dir ? w_ih_b : w_ih_f;
  const float* Whh = dir ? w_hh_b : w_hh_f;
  const float* bias = dir ? b_b : b_f;

  // weights: per wave, all 4 gates x its K-quarter (4 kt of 32) x split hi/lo
  f16x8 whh_h[4][4], whh_l[4][4], wih_h[4][4], wih_l[4][4];
#pragma unroll
  for (int gt = 0; gt < 4; ++gt) {
    const size_t r = (size_t)(gt * 512 + u0 + n) * 512 + kq;
#pragma unroll
    for (int q = 0; q < 4; ++q) {
      const float* ph = Whh + r + q * 32;
      const float* pi = Wih + r + q * 32;
      f16x8 a, b, c, d;
#pragma unroll
      for (int j = 0; j < 8; ++j) {
        HL s1 = splitH(ph[j]);
        HL s2 = splitH(pi[j]);
        a[j] = s1.h; b[j] = s1.l;
        c[j] = s2.h; d[j] = s2.l;
      }
      whh_h[gt][q] = a; whh_l[gt][q] = b; wih_h[gt][q] = c; wih_l[gt][q] = d;
    }
  }
#pragma unroll
  for (int gt = 0; gt < 4; ++gt)
#pragma unroll
    for (int q = 0; q < 4; ++q)
      asm volatile("" : "+v"(whh_h[gt][q]), "+v"(whh_l[gt][q]),
                        "+v"(wih_h[gt][q]), "+v"(wih_l[gt][q]));

  const int bb = tid >> 4, uu = tid & 15;          // gate-math cell
  const float bi = bias[u0 + uu];
  const float bf = bias[512 + u0 + uu];
  const float bg = bias[1024 + u0 + uu];
  const float bo = bias[1536 + u0 + uu];
  float c_st = 0.f;

  const size_t gslot = (size_t)g * T_;
  const size_t yrow = (size_t)(bh * 16 + n) * T_;
  const int rq = (lane >> 4) * 4;

  // ---- prologue: load x-fragments for step 0 (wave's quarter only) --------
  f16x8 xf0, xf1, xf2, xf3;
  {
    const int t0 = dir ? (T_ - 1) : 0;
    const f16* xb = Y + (yrow + t0) * 512 + kq;
    xf0 = *(const f16x8*)(xb);
    xf1 = *(const f16x8*)(xb + 32);
    xf2 = *(const f16x8*)(xb + 64);
    xf3 = *(const f16x8*)(xb + 96);
  }

  for (int s = 0; s < T_; ++s) {
    const int par = s & 1;
    f32x4 a0 = {0,0,0,0}, a1 = {0,0,0,0}, a2 = {0,0,0,0}, a3 = {0,0,0,0};

    // ---- IH MFMA first (no h dependency; runs while h(s-1) is in flight) --
    {
      f16x8 xq[4] = {xf0, xf1, xf2, xf3};
#pragma unroll
      for (int q = 0; q < 4; ++q) {
        a0 = __builtin_amdgcn_mfma_f32_16x16x32_f16(xq[q], wih_h[0][q], a0, 0, 0, 0);
        a0 = __builtin_amdgcn_mfma_f32_16x16x32_f16(xq[q], wih_l[0][q], a0, 0, 0, 0);
        a1 = __builtin_amdgcn_mfma_f32_16x16x32_f16(xq[q], wih_h[1][q], a1, 0, 0, 0);
        a1 = __builtin_amdgcn_mfma_f32_16x16x32_f16(xq[q], wih_l[1][q], a1, 0, 0, 0);
        a2 = __builtin_amdgcn_mfma_f32_16x16x32_f16(xq[q], wih_h[2][q], a2, 0, 0, 0);
        a2 = __builtin_amdgcn_mfma_f32_16x16x32_f16(xq[q], wih_l[2][q], a2, 0, 0, 0);
        a3 = __builtin_amdgcn_mfma_f32_16x16x32_f16(xq[q], wih_h[3][q], a3, 0, 0, 0);
        a3 = __builtin_amdgcn_mfma_f32_16x16x32_f16(xq[q], wih_l[3][q], a3, 0, 0, 0);
      }
    }

    // ---- prefetch x(s+1): poll + HH + gates cover its latency -------------
    if (s + 1 < T_) {
      const int t1 = dir ? (T_ - 2 - s) : (s + 1);
      const f16* xb = Y + (yrow + t1) * 512 + kq;
      xf0 = *(const f16x8*)(xb);
      xf1 = *(const f16x8*)(xb + 32);
      xf2 = *(const f16x8*)(xb + 64);
      xf3 = *(const f16x8*)(xb + 96);
    }

    // ---- 2-deep pipelined poll of own K-slice of h(s-1) -------------------
    if (s > 0) {
      const u64* hp = (const u64*)(hT + ((gslot + (s - 1)) * 16 + n) * 512 + kq);
      u32v4 dec[4];
      {
        u64 sA[8], sB[8];
        poll_issue(hp, sA);
        for (;;) {
          poll_issue(hp, sB);                 // in flight while A is checked
          if (!__any(poll_check(sA, dec))) break;
          poll_issue(hp, sA);                 // in flight while B is checked
          if (!__any(poll_check(sB, dec))) break;
        }
      }
      // HH MFMA: 4 gates x 4 kt x split, A = decoded h fragments
#pragma unroll
      for (int q = 0; q < 4; ++q) {
        f16x8 hf = __builtin_bit_cast(f16x8, dec[q]);
        a0 = __builtin_amdgcn_mfma_f32_16x16x32_f16(hf, whh_h[0][q], a0, 0, 0, 0);
        a0 = __builtin_amdgcn_mfma_f32_16x16x32_f16(hf, whh_l[0][q], a0, 0, 0, 0);
        a1 = __builtin_amdgcn_mfma_f32_16x16x32_f16(hf, whh_h[1][q], a1, 0, 0, 0);
        a1 = __builtin_amdgcn_mfma_f32_16x16x32_f16(hf, whh_l[1][q], a1, 0, 0, 0);
        a2 = __builtin_amdgcn_mfma_f32_16x16x32_f16(hf, whh_h[2][q], a2, 0, 0, 0);
        a2 = __builtin_amdgcn_mfma_f32_16x16x32_f16(hf, whh_l[2][q], a2, 0, 0, 0);
        a3 = __builtin_amdgcn_mfma_f32_16x16x32_f16(hf, whh_h[3][q], a3, 0, 0, 0);
        a3 = __builtin_amdgcn_mfma_f32_16x16x32_f16(hf, whh_l[3][q], a3, 0, 0, 0);
      }
    }

    // ---- write per-wave partials, single barrier ---------------------------
#pragma unroll
    for (int q = 0; q < 4; ++q) {
      g_lds[par][0][wv][rq + q][n] = a0[q];
      g_lds[par][1][wv][rq + q][n] = a1[q];
      g_lds[par][2][wv][rq + q][n] = a2[q];
      g_lds[par][3][wv][rq + q][n] = a3[q];
    }
    __syncthreads();

    // ---- gate math: sum 4 wave-partials per gate, update c, publish --------
    {
      float gi = g_lds[par][0][0][bb][uu] + g_lds[par][0][1][bb][uu] +
                 g_lds[par][0][2][bb][uu] + g_lds[par][0][3][bb][uu] + bi;
      float gf = g_lds[par][1][0][bb][uu] + g_lds[par][1][1][bb][uu] +
                 g_lds[par][1][2][bb][uu] + g_lds[par][1][3][bb][uu] + bf;
      float gg = g_lds[par][2][0][bb][uu] + g_lds[par][2][1][bb][uu] +
                 g_lds[par][2][2][bb][uu] + g_lds[par][2][3][bb][uu] + bg;
      float go = g_lds[par][3][0][bb][uu] + g_lds[par][3][1][bb][uu] +
                 g_lds[par][3][2][bb][uu] + g_lds[par][3][3][bb][uu] + bo;
      c_st = sigm(gf) * c_st + sigm(gi) * tanh_(gg);
      f16 h16 = (f16)(sigm(go) * tanh_(c_st));
      u32 enc = (u32)(u16)(__builtin_bit_cast(u16, h16) + 1);
      u32 o1 = (u32)__shfl_xor((int)enc, 1);
      u32 p2 = (uu & 1) ? (o1 | (enc << 16)) : (enc | (o1 << 16));
      u32 o2 = (u32)__shfl_xor((int)p2, 2);
      u64 q64 = (uu & 2) ? ((u64)o2 | ((u64)p2 << 32))
                         : ((u64)p2 | ((u64)o2 << 32));
      if ((uu & 3) == 0) {
        u64* dst = (u64*)(hT + ((gslot + s) * 16 + bb) * 512 + u0 + uu);
        __hip_atomic_store(dst, q64, __ATOMIC_RELAXED, __HIP_MEMORY_SCOPE_AGENT);
      }
    }
  }
}

// ---------------- final linear: out = decode(hT) @ lin_w^T + lin_b ----------
// hT is written with agent-scope (L2-bypassing) stores in k_lstm, so it MUST
// be read with agent-scope loads here too: plain loads can hit stale XCD-L2
// lines (harness 0xAA poison / memset zeros) that sc1 stores never update.
__global__ __launch_bounds__(256) void k_final(const u16* __restrict__ hT,
                                               const f16* __restrict__ LH,
                                               const f16* __restrict__ LL,
                                               const float* __restrict__ lin_b,
                                               float* __restrict__ out) {
  __shared__ f16 As[64][40];
  __shared__ f16 BsH[80][40];
  __shared__ f16 BsL[80][40];
  const int tid = threadIdx.x;
  const int bt0 = blockIdx.x * 64;
  const int b = bt0 >> 11;                 // batch
  const int bh = b >> 4, bi = b & 15;
  const int lane = tid & 63, wave = tid >> 6;
  const int n = lane & 15, klo = (lane >> 4) * 8;
  f32x4 acc[5] = {{0,0,0,0},{0,0,0,0},{0,0,0,0},{0,0,0,0},{0,0,0,0}};
  float bl[5];
#pragma unroll
  for (int nt = 0; nt < 5; ++nt) bl[nt] = lin_b[nt * 16 + n];
  const int ar = tid >> 2, aoff = (tid & 3) * 8;
  const int tr = (bt0 & 2047) + ar;
  for (int kt = 0; kt < 32; ++kt) {
    __syncthreads();
    {
      size_t src;
      if (kt < 16)
        src = ((size_t)(bh * T_ + tr) * 16 + bi) * 512 + kt * 32 + aoff;
      else
        src = ((size_t)((2 + bh) * T_ + (T_ - 1 - tr)) * 16 + bi) * 512 +
              (kt - 16) * 32 + aoff;
      const u64* p = (const u64*)(hT + src);
      u64 a = __hip_atomic_load(p, __ATOMIC_RELAXED, __HIP_MEMORY_SCOPE_AGENT);
      u64 b2 = __hip_atomic_load(p + 1, __ATOMIC_RELAXED, __HIP_MEMORY_SCOPE_AGENT);
      u32v4 v;
      v[0] = (u32)a; v[1] = (u32)(a >> 32);
      v[2] = (u32)b2; v[3] = (u32)(b2 >> 32);
#pragma unroll
      for (int j = 0; j < 4; ++j) v[j] -= 0x00010001u;
      *(u32v4*)&As[ar][aoff] = v;
    }
    {
      int row = tid >> 2, off = (tid & 3) * 8;
      *(u32v4*)&BsH[row][off] = *(const u32v4*)(LH + (size_t)row * 1024 + kt * 32 + off);
      *(u32v4*)&BsL[row][off] = *(const u32v4*)(LL + (size_t)row * 1024 + kt * 32 + off);
      if (tid < 64) {
        int c2 = 256 + tid, row2 = c2 >> 2, off2 = (c2 & 3) * 8;
        *(u32v4*)&BsH[row2][off2] = *(const u32v4*)(LH + (size_t)row2 * 1024 + kt * 32 + off2);
        *(u32v4*)&BsL[row2][off2] = *(const u32v4*)(LL + (size_t)row2 * 1024 + kt * 32 + off2);
      }
    }
    __syncthreads();
    f16x8 af = *(const f16x8*)&As[wave * 16 + n][klo];
#pragma unroll
    for (int nt = 0; nt < 5; ++nt) {
      f16x8 bh_ = *(const f16x8*)&BsH[nt * 16 + n][klo];
      f16x8 bl_ = *(const f16x8*)&BsL[nt * 16 + n][klo];
      acc[nt] = __builtin_amdgcn_mfma_f32_16x16x32_f16(af, bh_, acc[nt], 0, 0, 0);
      acc[nt] = __builtin_amdgcn_mfma_f32_16x16x32_f16(af, bl_, acc[nt], 0, 0, 0);
    }
  }
  const int rq = (lane >> 4) * 4;
#pragma unroll
  for (int nt = 0; nt < 5; ++nt)
#pragma unroll
    for (int q = 0; q < 4; ++q)
      out[(size_t)(bt0 + wave * 16 + rq + q) * NM_ + nt * 16 + n] = acc[nt][q] + bl[nt];
}

// ---------------- launcher ---------------------------------------------------
extern "C" void kernel_launch(void* const* d_in, const int* in_sizes, int n_in,
                              void* d_out, int out_size, void* d_ws, size_t ws_size,
                              hipStream_t stream) {
  const float* x_in   = (const float*)d_in[0];
  const float* emb    = (const float*)d_in[1];
  const float* conv_w = (const float*)d_in[2];
  const float* bn_g   = (const float*)d_in[3];
  const float* bn_b   = (const float*)d_in[4];
  const float* w_ih_f = (const float*)d_in[5];
  const float* w_hh_f = (const float*)d_in[6];
  const float* b_f    = (const float*)d_in[7];
  const float* w_ih_b = (const float*)d_in[8];
  const float* w_hh_b = (const float*)d_in[9];
  const float* b_b    = (const float*)d_in[10];
  const float* lin_w  = (const float*)d_in[11];
  const float* lin_b  = (const float*)d_in[12];
  float* out = (float*)d_out;

  char* ws = (char*)d_ws;
  size_t o = 0;
  auto alloc = [&](size_t bytes) {
    void* p = ws + o;
    o = (o + bytes + 255) & ~(size_t)255;
    return p;
  };
  f16* WcH  = (f16*)alloc(512 * 384 * 2);
  f16* WcL  = (f16*)alloc(512 * 384 * 2);
  f16* LinH = (f16*)alloc(80 * 1024 * 2);
  f16* LinL = (f16*)alloc(80 * 1024 * 2);
  f16* Y    = (f16*)alloc((size_t)BT_ * CD_ * 2);          // 64 MiB
  u16* hT   = (u16*)alloc((size_t)4 * T_ * 16 * 512 * 2);  // 128 MiB
  float* sums  = (float*)alloc(512 * 4);
  float* sumsq = (float*)alloc(512 * 4);
  float* scl   = (float*)alloc(512 * 4);
  float* shf   = (float*)alloc(512 * 4);
  if (o > ws_size) return;  // workspace too small -> loud failure

  (void)hipMemsetAsync(sums, 0, 512 * 4, stream);
  (void)hipMemsetAsync(sumsq, 0, 512 * 4, stream);
  (void)hipMemsetAsync(hT, 0, (size_t)4 * T_ * 16 * 512 * 2, stream);

  k_compose<<<768, 256, 0, stream>>>(emb, conv_w, WcH, WcL);
  k_packlin<<<320, 256, 0, stream>>>(lin_w, LinH, LinL);
  k_conv<<<dim3(2048, 8), 256, 0, stream>>>(x_in, WcH, WcL, Y);
  k_bnstats<<<1024, 256, 0, stream>>>(Y, sums, sumsq);
  k_bnscale<<<2, 256, 0, stream>>>(sums, sumsq, bn_g, bn_b, scl, shf);
  k_bnapply<<<2048, 256, 0, stream>>>(Y, scl, shf);

  // plain launch: no grid-sync API used; 128 blocks @ 1 block/CU are
  // trivially co-resident on 256 CUs.
  k_lstm<<<128, 256, 0, stream>>>(Y, w_ih_f, w_hh_f, b_f, w_ih_b, w_hh_b,
                                  b_b, hT);
  k_final<<<1024, 256, 0, stream>>>(hT, LinH, LinL, lin_b, out);
}

// Round 14
// 7511.307 us; speedup vs baseline: 1.0516x; 1.0516x over previous
//
#include <hip/hip_runtime.h>

typedef unsigned int u32;
typedef unsigned short u16;
typedef unsigned long long u64;
typedef _Float16 f16;
typedef __attribute__((ext_vector_type(4))) float f32x4;
typedef __attribute__((ext_vector_type(8))) _Float16 f16x8;
typedef __attribute__((ext_vector_type(4))) _Float16 f16x4;
typedef __attribute__((ext_vector_type(4))) u32 u32v4;

#define DEVI static __device__ __forceinline__

constexpr int B_ = 32, T_ = 2048, NS_ = 128, CD_ = 512, NM_ = 80;
constexpr int BT_ = B_ * T_;        // 65536

struct HL { f16 h, l; };
DEVI HL splitH(float f) {
  HL r;
  r.h = (f16)f;
  r.l = (f16)(f - (float)r.h);
  return r;
}
DEVI float h2f_lo(u32 u) { return (float)__builtin_bit_cast(f16, (u16)(u & 0xffffu)); }
DEVI float h2f_hi(u32 u) { return (float)__builtin_bit_cast(f16, (u16)(u >> 16)); }
DEVI u32 pack2h(float a, float b) {
  u16 x = __builtin_bit_cast(u16, (f16)a);
  u16 y = __builtin_bit_cast(u16, (f16)b);
  return (u32)x | ((u32)y << 16);
}
DEVI float sigm(float x) { return 1.f / (1.f + __expf(-x)); }
DEVI float tanh_(float x) {
  float e = __expf(2.f * x);
  return 1.f - 2.f / (e + 1.f);
}

// ---- compose conv(emb(.)): W2[o][kk*128+n] = sum_e emb[n][e]*cw[o][e][kk] --
__global__ __launch_bounds__(256) void k_compose(const float* __restrict__ emb,
                                                 const float* __restrict__ cw,
                                                 f16* __restrict__ WH,
                                                 f16* __restrict__ WL) {
  int idx = blockIdx.x * 256 + threadIdx.x;        // 512*384 = 196608
  int o = idx / 384, k = idx - o * 384;
  int kk = k >> 7, n = k & 127;
  const float* er = emb + n * 128;
  const float* wr = cw + (size_t)o * 384 + kk;     // stride 3 over e
  float a = 0.f;
  for (int e = 0; e < 128; ++e) a += er[e] * wr[e * 3];
  HL s = splitH(a);
  WH[(size_t)o * 384 + k] = s.h;
  WL[(size_t)o * 384 + k] = s.l;
}

__global__ __launch_bounds__(256) void k_packlin(const float* __restrict__ lw,
                                                 f16* __restrict__ LH,
                                                 f16* __restrict__ LL) {
  int i = blockIdx.x * 256 + threadIdx.x;          // 80*1024 = 81920
  HL s = splitH(lw[i]);
  LH[i] = s.h;
  LL[i] = s.l;
}

// ---- conv as GEMM (split-f16): Y[bt][o] = relu(Xrow(t..t+2) . Wc[o]) -------
__global__ __launch_bounds__(256) void k_conv(const float* __restrict__ x,
                                              const f16* __restrict__ WH,
                                              const f16* __restrict__ WL,
                                              f16* __restrict__ Y) {
  __shared__ f16 XsH[34][136];
  __shared__ f16 XsL[34][136];
  const int tid = threadIdx.x;
  const int b = blockIdx.x >> 6;
  const int t0 = (blockIdx.x & 63) * 32;
  const int n0 = blockIdx.y * 64;
  const int lane = tid & 63, wave = tid >> 6;
  const int n = lane & 15, klo = (lane >> 4) * 8;

  f16x8 bH[12], bL[12];
  {
    const size_t brow = (size_t)(n0 + wave * 16 + n) * 384 + klo;
#pragma unroll
    for (int kt = 0; kt < 12; ++kt) {
      bH[kt] = *(const f16x8*)(WH + brow + kt * 32);
      bL[kt] = *(const f16x8*)(WL + brow + kt * 32);
    }
  }
  for (int idx = tid; idx < 34 * 32; idx += 256) {
    int row = idx >> 5, q = idx & 31;
    int trow = t0 - 1 + row;
    f16x4 vh = {0, 0, 0, 0}, vl = {0, 0, 0, 0};
    if (trow >= 0 && trow < T_) {
      float4 v = *(const float4*)(x + ((size_t)b * T_ + trow) * NS_ + 4 * q);
      HL s0 = splitH(v.x), s1 = splitH(v.y), s2 = splitH(v.z), s3 = splitH(v.w);
      vh[0] = s0.h; vl[0] = s0.l;
      vh[1] = s1.h; vl[1] = s1.l;
      vh[2] = s2.h; vl[2] = s2.l;
      vh[3] = s3.h; vl[3] = s3.l;
    }
    *(f16x4*)&XsH[row][4 * q] = vh;
    *(f16x4*)&XsL[row][4 * q] = vl;
  }
  __syncthreads();

  f32x4 aH_[2] = {{0,0,0,0},{0,0,0,0}}, aM_[2] = {{0,0,0,0},{0,0,0,0}};
#pragma unroll
  for (int kt = 0; kt < 12; ++kt) {
    int kk = kt >> 2, i = (kt & 3) * 32 + klo;
#pragma unroll
    for (int m = 0; m < 2; ++m) {
      f16x8 ah = *(const f16x8*)&XsH[m * 16 + n + kk][i];
      f16x8 al = *(const f16x8*)&XsL[m * 16 + n + kk][i];
      aH_[m] = __builtin_amdgcn_mfma_f32_16x16x32_f16(ah, bH[kt], aH_[m], 0, 0, 0);
      aM_[m] = __builtin_amdgcn_mfma_f32_16x16x32_f16(ah, bL[kt], aM_[m], 0, 0, 0);
      aM_[m] = __builtin_amdgcn_mfma_f32_16x16x32_f16(al, bH[kt], aM_[m], 0, 0, 0);
    }
  }
  const int rq = (lane >> 4) * 4;
#pragma unroll
  for (int m = 0; m < 2; ++m)
#pragma unroll
    for (int q = 0; q < 4; ++q) {
      int rowg = blockIdx.x * 32 + m * 16 + rq + q;
      float v = aH_[m][q] + aM_[m][q];
      Y[(size_t)rowg * CD_ + n0 + wave * 16 + n] = (f16)(v > 0.f ? v : 0.f);
    }
}

// ---------------- BN stats / scale / apply ---------------------------------
__global__ __launch_bounds__(256) void k_bnstats(const f16* __restrict__ Y,
                                                 float* __restrict__ sums,
                                                 float* __restrict__ sumsq) {
  const u32* Y32 = (const u32*)Y;
  int r0 = blockIdx.x * 64;
  float a0 = 0, a1 = 0, q0 = 0, q1 = 0;
  for (int i = 0; i < 64; ++i) {
    u32 v = Y32[(size_t)(r0 + i) * 256 + threadIdx.x];
    float x0 = h2f_lo(v), x1 = h2f_hi(v);
    a0 += x0; a1 += x1; q0 += x0 * x0; q1 += x1 * x1;
  }
  int c = threadIdx.x * 2;
  atomicAdd(&sums[c], a0); atomicAdd(&sums[c + 1], a1);
  atomicAdd(&sumsq[c], q0); atomicAdd(&sumsq[c + 1], q1);
}

__global__ void k_bnscale(const float* __restrict__ sums, const float* __restrict__ sumsq,
                          const float* __restrict__ g, const float* __restrict__ be,
                          float* __restrict__ scl, float* __restrict__ shf) {
  int c = blockIdx.x * 256 + threadIdx.x;
  if (c < CD_) {
    float m = sums[c] * (1.f / 65536.f);
    float v = sumsq[c] * (1.f / 65536.f) - m * m;
    float s = g[c] * rsqrtf(v + 1e-5f);
    scl[c] = s; shf[c] = be[c] - m * s;
  }
}

__global__ __launch_bounds__(256) void k_bnapply(f16* __restrict__ Y,
                                                 const float* __restrict__ scl,
                                                 const float* __restrict__ shf) {
  const int total = BT_ * CD_ / 8;
  int idx0 = blockIdx.x * 256 + threadIdx.x;
  int c0 = (idx0 & 63) * 8;
  float sc[8], sh[8];
#pragma unroll
  for (int j = 0; j < 8; ++j) { sc[j] = scl[c0 + j]; sh[j] = shf[c0 + j]; }
  u32v4* Yv = (u32v4*)Y;
  for (int idx = idx0; idx < total; idx += 2048 * 256) {
    u32v4 v = Yv[idx], o;
#pragma unroll
    for (int j = 0; j < 4; ++j) {
      float lo = h2f_lo(v[j]) * sc[2 * j] + sh[2 * j];
      float hi = h2f_hi(v[j]) * sc[2 * j + 1] + sh[2 * j + 1];
      o[j] = pack2h(lo, hi);
    }
    Yv[idx] = o;
  }
}

// ---------------- persistent bidirectional LSTM (K-split waves) -------------
// 128 blocks x 256 thr, 4 groups (dir x batch-half) of 32 blocks; block owns
// 16 units. Wave = K-quarter (128 units), all 4 gates over its slice; each
// wave polls only its own slice (8 producer blocks), decodes in registers,
// feeds MFMA directly. Parity-double-buffered partial LDS -> ONE barrier/step.
// h published as bits(f16)+1 into zeroed T-deep slots via relaxed agent
// stores (sc1, L2-bypass); ALL hT readers (here and k_final) use the same
// agent-scope loads. x(s+1) prefetch issues RIGHT AFTER poll-success (xf
// snapshot to xq first) so ~2.5us of HH+barrier+gates+next-poll cover its
// latency before any waitcnt consumer (next iteration's snapshot).
__global__ __launch_bounds__(256, 1) void k_lstm(
    const f16* __restrict__ Y, const float* __restrict__ w_ih_f,
    const float* __restrict__ w_hh_f, const float* __restrict__ b_f,
    const float* __restrict__ w_ih_b, const float* __restrict__ w_hh_b,
    const float* __restrict__ b_b, u16* __restrict__ hT) {
  __shared__ float g_lds[2][4][4][16][17];  // [parity][gate][wave][row][col]
  const int tid = threadIdx.x;
  const int lane = tid & 63, wv = tid >> 6;
  const int bid = blockIdx.x;
  const int g = bid >> 5;                          // group 0..3
  const int dir = g >> 1, bh = g & 1;
  const int u0 = (bid & 31) * 16;                  // hidden-unit base
  const int n = lane & 15;                         // batch row / unit col
  const int klo = (lane >> 4) * 8;
  const int kq = wv * 128 + klo;                   // wave K-slice + lane offset

  const float* Wih = dir ? w_ih_b : w_ih_f;
  const float* Whh = dir ? w_hh_b : w_hh_f;
  const float* bias = dir ? b_b : b_f;

  // weights: per wave, all 4 gates x its K-quarter (4 kt of 32) x split hi/lo
  f16x8 whh_h[4][4], whh_l[4][4], wih_h[4][4], wih_l[4][4];
#pragma unroll
  for (int gt = 0; gt < 4; ++gt) {
    const size_t r = (size_t)(gt * 512 + u0 + n) * 512 + kq;
#pragma unroll
    for (int q = 0; q < 4; ++q) {
      const float* ph = Whh + r + q * 32;
      const float* pi = Wih + r + q * 32;
      f16x8 a, b, c, d;
#pragma unroll
      for (int j = 0; j < 8; ++j) {
        HL s1 = splitH(ph[j]);
        HL s2 = splitH(pi[j]);
        a[j] = s1.h; b[j] = s1.l;
        c[j] = s2.h; d[j] = s2.l;
      }
      whh_h[gt][q] = a; whh_l[gt][q] = b; wih_h[gt][q] = c; wih_l[gt][q] = d;
    }
  }
#pragma unroll
  for (int gt = 0; gt < 4; ++gt)
#pragma unroll
    for (int q = 0; q < 4; ++q)
      asm volatile("" : "+v"(whh_h[gt][q]), "+v"(whh_l[gt][q]),
                        "+v"(wih_h[gt][q]), "+v"(wih_l[gt][q]));

  const int bb = tid >> 4, uu = tid & 15;          // gate-math cell
  const float bi = bias[u0 + uu];
  const float bf = bias[512 + u0 + uu];
  const float bg = bias[1024 + u0 + uu];
  const float bo = bias[1536 + u0 + uu];
  float c_st = 0.f;

  const size_t gslot = (size_t)g * T_;
  const size_t yrow = (size_t)(bh * 16 + n) * T_;
  const int rq = (lane >> 4) * 4;

  // ---- prologue: load x-fragments for step 0 (wave's quarter only) --------
  f16x8 xf0, xf1, xf2, xf3;
  {
    const int t0 = dir ? (T_ - 1) : 0;
    const f16* xb = Y + (yrow + t0) * 512 + kq;
    xf0 = *(const f16x8*)(xb);
    xf1 = *(const f16x8*)(xb + 32);
    xf2 = *(const f16x8*)(xb + 64);
    xf3 = *(const f16x8*)(xb + 96);
  }

  for (int s = 0; s < T_; ++s) {
    const int par = s & 1;
    f32x4 a0 = {0,0,0,0}, a1 = {0,0,0,0}, a2 = {0,0,0,0}, a3 = {0,0,0,0};

    // ---- poll own K-slice of h(s-1); decoded registers feed MFMA directly -
    u32v4 dec[4];
    if (s > 0) {
      const u16* hrow = hT + ((gslot + (s - 1)) * 16 + n) * 512 + kq;
      for (;;) {
        u32 bad = 0;
#pragma unroll
        for (int q = 0; q < 4; ++q) {
          const u64* p = (const u64*)(hrow + q * 32);
          u64 a = __hip_atomic_load(p, __ATOMIC_RELAXED, __HIP_MEMORY_SCOPE_AGENT);
          u64 b = __hip_atomic_load(p + 1, __ATOMIC_RELAXED, __HIP_MEMORY_SCOPE_AGENT);
          u32 w0 = (u32)a, w1 = (u32)(a >> 32), w2 = (u32)b, w3 = (u32)(b >> 32);
          u32 d0 = w0 - 0x00010001u, d1 = w1 - 0x00010001u;
          u32 d2 = w2 - 0x00010001u, d3 = w3 - 0x00010001u;
          bad |= (d0 & ~w0 & 0x80008000u) | (d1 & ~w1 & 0x80008000u) |
                 (d2 & ~w2 & 0x80008000u) | (d3 & ~w3 & 0x80008000u);
          dec[q][0] = d0; dec[q][1] = d1; dec[q][2] = d2; dec[q][3] = d3;
        }
        if (!__any(bad)) break;
      }
    }

    // ---- snapshot xf -> xq, then issue x(s+1) prefetch (covered by rest of
    //      this step + next poll; next waitcnt consumer is next snapshot) ----
    f16x8 xq0 = xf0, xq1 = xf1, xq2 = xf2, xq3 = xf3;
    if (s + 1 < T_) {
      const int t1 = dir ? (T_ - 2 - s) : (s + 1);
      const f16* xb = Y + (yrow + t1) * 512 + kq;
      xf0 = *(const f16x8*)(xb);
      xf1 = *(const f16x8*)(xb + 32);
      xf2 = *(const f16x8*)(xb + 64);
      xf3 = *(const f16x8*)(xb + 96);
    }

    // ---- HH MFMA: 4 gates x 4 kt x split, A = decoded h fragments ---------
    if (s > 0) {
#pragma unroll
      for (int q = 0; q < 4; ++q) {
        f16x8 hf = __builtin_bit_cast(f16x8, dec[q]);
        a0 = __builtin_amdgcn_mfma_f32_16x16x32_f16(hf, whh_h[0][q], a0, 0, 0, 0);
        a0 = __builtin_amdgcn_mfma_f32_16x16x32_f16(hf, whh_l[0][q], a0, 0, 0, 0);
        a1 = __builtin_amdgcn_mfma_f32_16x16x32_f16(hf, whh_h[1][q], a1, 0, 0, 0);
        a1 = __builtin_amdgcn_mfma_f32_16x16x32_f16(hf, whh_l[1][q], a1, 0, 0, 0);
        a2 = __builtin_amdgcn_mfma_f32_16x16x32_f16(hf, whh_h[2][q], a2, 0, 0, 0);
        a2 = __builtin_amdgcn_mfma_f32_16x16x32_f16(hf, whh_l[2][q], a2, 0, 0, 0);
        a3 = __builtin_amdgcn_mfma_f32_16x16x32_f16(hf, whh_h[3][q], a3, 0, 0, 0);
        a3 = __builtin_amdgcn_mfma_f32_16x16x32_f16(hf, whh_l[3][q], a3, 0, 0, 0);
      }
    }

    // ---- IH MFMA from snapshot registers ----------------------------------
    {
      f16x8 xqv[4] = {xq0, xq1, xq2, xq3};
#pragma unroll
      for (int q = 0; q < 4; ++q) {
        a0 = __builtin_amdgcn_mfma_f32_16x16x32_f16(xqv[q], wih_h[0][q], a0, 0, 0, 0);
        a0 = __builtin_amdgcn_mfma_f32_16x16x32_f16(xqv[q], wih_l[0][q], a0, 0, 0, 0);
        a1 = __builtin_amdgcn_mfma_f32_16x16x32_f16(xqv[q], wih_h[1][q], a1, 0, 0, 0);
        a1 = __builtin_amdgcn_mfma_f32_16x16x32_f16(xqv[q], wih_l[1][q], a1, 0, 0, 0);
        a2 = __builtin_amdgcn_mfma_f32_16x16x32_f16(xqv[q], wih_h[2][q], a2, 0, 0, 0);
        a2 = __builtin_amdgcn_mfma_f32_16x16x32_f16(xqv[q], wih_l[2][q], a2, 0, 0, 0);
        a3 = __builtin_amdgcn_mfma_f32_16x16x32_f16(xqv[q], wih_h[3][q], a3, 0, 0, 0);
        a3 = __builtin_amdgcn_mfma_f32_16x16x32_f16(xqv[q], wih_l[3][q], a3, 0, 0, 0);
      }
    }

    // ---- write per-wave partials, single barrier ---------------------------
#pragma unroll
    for (int q = 0; q < 4; ++q) {
      g_lds[par][0][wv][rq + q][n] = a0[q];
      g_lds[par][1][wv][rq + q][n] = a1[q];
      g_lds[par][2][wv][rq + q][n] = a2[q];
      g_lds[par][3][wv][rq + q][n] = a3[q];
    }
    __syncthreads();

    // ---- gate math: sum 4 wave-partials per gate, update c, publish --------
    {
      float gi = g_lds[par][0][0][bb][uu] + g_lds[par][0][1][bb][uu] +
                 g_lds[par][0][2][bb][uu] + g_lds[par][0][3][bb][uu] + bi;
      float gf = g_lds[par][1][0][bb][uu] + g_lds[par][1][1][bb][uu] +
                 g_lds[par][1][2][bb][uu] + g_lds[par][1][3][bb][uu] + bf;
      float gg = g_lds[par][2][0][bb][uu] + g_lds[par][2][1][bb][uu] +
                 g_lds[par][2][2][bb][uu] + g_lds[par][2][3][bb][uu] + bg;
      float go = g_lds[par][3][0][bb][uu] + g_lds[par][3][1][bb][uu] +
                 g_lds[par][3][2][bb][uu] + g_lds[par][3][3][bb][uu] + bo;
      c_st = sigm(gf) * c_st + sigm(gi) * tanh_(gg);
      f16 h16 = (f16)(sigm(go) * tanh_(c_st));
      u32 enc = (u32)(u16)(__builtin_bit_cast(u16, h16) + 1);
      u32 o1 = (u32)__shfl_xor((int)enc, 1);
      u32 p2 = (uu & 1) ? (o1 | (enc << 16)) : (enc | (o1 << 16));
      u32 o2 = (u32)__shfl_xor((int)p2, 2);
      u64 q64 = (uu & 2) ? ((u64)o2 | ((u64)p2 << 32))
                         : ((u64)p2 | ((u64)o2 << 32));
      if ((uu & 3) == 0) {
        u64* dst = (u64*)(hT + ((gslot + s) * 16 + bb) * 512 + u0 + uu);
        __hip_atomic_store(dst, q64, __ATOMIC_RELAXED, __HIP_MEMORY_SCOPE_AGENT);
      }
    }
  }
}

// ---------------- final linear: out = decode(hT) @ lin_w^T + lin_b ----------
// hT is written with agent-scope (L2-bypassing) stores in k_lstm, so it MUST
// be read with agent-scope loads here too: plain loads can hit stale XCD-L2
// lines (harness 0xAA poison / memset zeros) that sc1 stores never update.
__global__ __launch_bounds__(256) void k_final(const u16* __restrict__ hT,
                                               const f16* __restrict__ LH,
                                               const f16* __restrict__ LL,
                                               const float* __restrict__ lin_b,
                                               float* __restrict__ out) {
  __shared__ f16 As[64][40];
  __shared__ f16 BsH[80][40];
  __shared__ f16 BsL[80][40];
  const int tid = threadIdx.x;
  const int bt0 = blockIdx.x * 64;
  const int b = bt0 >> 11;                 // batch
  const int bh = b >> 4, bi = b & 15;
  const int lane = tid & 63, wave = tid >> 6;
  const int n = lane & 15, klo = (lane >> 4) * 8;
  f32x4 acc[5] = {{0,0,0,0},{0,0,0,0},{0,0,0,0},{0,0,0,0},{0,0,0,0}};
  float bl[5];
#pragma unroll
  for (int nt = 0; nt < 5; ++nt) bl[nt] = lin_b[nt * 16 + n];
  const int ar = tid >> 2, aoff = (tid & 3) * 8;
  const int tr = (bt0 & 2047) + ar;
  for (int kt = 0; kt < 32; ++kt) {
    __syncthreads();
    {
      size_t src;
      if (kt < 16)
        src = ((size_t)(bh * T_ + tr) * 16 + bi) * 512 + kt * 32 + aoff;
      else
        src = ((size_t)((2 + bh) * T_ + (T_ - 1 - tr)) * 16 + bi) * 512 +
              (kt - 16) * 32 + aoff;
      const u64* p = (const u64*)(hT + src);
      u64 a = __hip_atomic_load(p, __ATOMIC_RELAXED, __HIP_MEMORY_SCOPE_AGENT);
      u64 b2 = __hip_atomic_load(p + 1, __ATOMIC_RELAXED, __HIP_MEMORY_SCOPE_AGENT);
      u32v4 v;
      v[0] = (u32)a; v[1] = (u32)(a >> 32);
      v[2] = (u32)b2; v[3] = (u32)(b2 >> 32);
#pragma unroll
      for (int j = 0; j < 4; ++j) v[j] -= 0x00010001u;
      *(u32v4*)&As[ar][aoff] = v;
    }
    {
      int row = tid >> 2, off = (tid & 3) * 8;
      *(u32v4*)&BsH[row][off] = *(const u32v4*)(LH + (size_t)row * 1024 + kt * 32 + off);
      *(u32v4*)&BsL[row][off] = *(const u32v4*)(LL + (size_t)row * 1024 + kt * 32 + off);
      if (tid < 64) {
        int c2 = 256 + tid, row2 = c2 >> 2, off2 = (c2 & 3) * 8;
        *(u32v4*)&BsH[row2][off2] = *(const u32v4*)(LH + (size_t)row2 * 1024 + kt * 32 + off2);
        *(u32v4*)&BsL[row2][off2] = *(const u32v4*)(LL + (size_t)row2 * 1024 + kt * 32 + off2);
      }
    }
    __syncthreads();
    f16x8 af = *(const f16x8*)&As[wave * 16 + n][klo];
#pragma unroll
    for (int nt = 0; nt < 5; ++nt) {
      f16x8 bh_ = *(const f16x8*)&BsH[nt * 16 + n][klo];
      f16x8 bl_ = *(const f16x8*)&BsL[nt * 16 + n][klo];
      acc[nt] = __builtin_amdgcn_mfma_f32_16x16x32_f16(af, bh_, acc[nt], 0, 0, 0);
      acc[nt] = __builtin_amdgcn_mfma_f32_16x16x32_f16(af, bl_, acc[nt], 0, 0, 0);
    }
  }
  const int rq = (lane >> 4) * 4;
#pragma unroll
  for (int nt = 0; nt < 5; ++nt)
#pragma unroll
    for (int q = 0; q < 4; ++q)
      out[(size_t)(bt0 + wave * 16 + rq + q) * NM_ + nt * 16 + n] = acc[nt][q] + bl[nt];
}

// ---------------- launcher ---------------------------------------------------
extern "C" void kernel_launch(void* const* d_in, const int* in_sizes, int n_in,
                              void* d_out, int out_size, void* d_ws, size_t ws_size,
                              hipStream_t stream) {
  const float* x_in   = (const float*)d_in[0];
  const float* emb    = (const float*)d_in[1];
  const float* conv_w = (const float*)d_in[2];
  const float* bn_g   = (const float*)d_in[3];
  const float* bn_b   = (const float*)d_in[4];
  const float* w_ih_f = (const float*)d_in[5];
  const float* w_hh_f = (const float*)d_in[6];
  const float* b_f    = (const float*)d_in[7];
  const float* w_ih_b = (const float*)d_in[8];
  const float* w_hh_b = (const float*)d_in[9];
  const float* b_b    = (const float*)d_in[10];
  const float* lin_w  = (const float*)d_in[11];
  const float* lin_b  = (const float*)d_in[12];
  float* out = (float*)d_out;

  char* ws = (char*)d_ws;
  size_t o = 0;
  auto alloc = [&](size_t bytes) {
    void* p = ws + o;
    o = (o + bytes + 255) & ~(size_t)255;
    return p;
  };
  f16* WcH  = (f16*)alloc(512 * 384 * 2);
  f16* WcL  = (f16*)alloc(512 * 384 * 2);
  f16* LinH = (f16*)alloc(80 * 1024 * 2);
  f16* LinL = (f16*)alloc(80 * 1024 * 2);
  f16* Y    = (f16*)alloc((size_t)BT_ * CD_ * 2);          // 64 MiB
  u16* hT   = (u16*)alloc((size_t)4 * T_ * 16 * 512 * 2);  // 128 MiB
  float* sums  = (float*)alloc(512 * 4);
  float* sumsq = (float*)alloc(512 * 4);
  float* scl   = (float*)alloc(512 * 4);
  float* shf   = (float*)alloc(512 * 4);
  if (o > ws_size) return;  // workspace too small -> loud failure

  (void)hipMemsetAsync(sums, 0, 512 * 4, stream);
  (void)hipMemsetAsync(sumsq, 0, 512 * 4, stream);
  (void)hipMemsetAsync(hT, 0, (size_t)4 * T_ * 16 * 512 * 2, stream);

  k_compose<<<768, 256, 0, stream>>>(emb, conv_w, WcH, WcL);
  k_packlin<<<320, 256, 0, stream>>>(lin_w, LinH, LinL);
  k_conv<<<dim3(2048, 8), 256, 0, stream>>>(x_in, WcH, WcL, Y);
  k_bnstats<<<1024, 256, 0, stream>>>(Y, sums, sumsq);
  k_bnscale<<<2, 256, 0, stream>>>(sums, sumsq, bn_g, bn_b, scl, shf);
  k_bnapply<<<2048, 256, 0, stream>>>(Y, scl, shf);

  // plain launch: no grid-sync API used; 128 blocks @ 1 block/CU are
  // trivially co-resident on 256 CUs.
  k_lstm<<<128, 256, 0, stream>>>(Y, w_ih_f, w_hh_f, b_f, w_ih_b, w_hh_b,
                                  b_b, hT);
  k_final<<<1024, 256, 0, stream>>>(hT, LinH, LinL, lin_b, out);
}

// Round 15
// 6916.998 us; speedup vs baseline: 1.1419x; 1.0859x over previous
//
#include <hip/hip_runtime.h>

typedef unsigned int u32;
typedef unsigned short u16;
typedef unsigned long long u64;
typedef _Float16 f16;
typedef __attribute__((ext_vector_type(4))) float f32x4;
typedef __attribute__((ext_vector_type(8))) _Float16 f16x8;
typedef __attribute__((ext_vector_type(4))) _Float16 f16x4;
typedef __attribute__((ext_vector_type(4))) u32 u32v4;

#define DEVI static __device__ __forceinline__

constexpr int B_ = 32, T_ = 2048, NS_ = 128, CD_ = 512, NM_ = 80;
constexpr int BT_ = B_ * T_;        // 65536

struct HL { f16 h, l; };
DEVI HL splitH(float f) {
  HL r;
  r.h = (f16)f;
  r.l = (f16)(f - (float)r.h);
  return r;
}
DEVI float h2f_lo(u32 u) { return (float)__builtin_bit_cast(f16, (u16)(u & 0xffffu)); }
DEVI float h2f_hi(u32 u) { return (float)__builtin_bit_cast(f16, (u16)(u >> 16)); }
DEVI u32 pack2h(float a, float b) {
  u16 x = __builtin_bit_cast(u16, (f16)a);
  u16 y = __builtin_bit_cast(u16, (f16)b);
  return (u32)x | ((u32)y << 16);
}
DEVI float sigm(float x) { return 1.f / (1.f + __expf(-x)); }
DEVI float tanh_(float x) {
  float e = __expf(2.f * x);
  return 1.f - 2.f / (e + 1.f);
}

// ---- compose conv(emb(.)): W2[o][kk*128+n] = sum_e emb[n][e]*cw[o][e][kk] --
__global__ __launch_bounds__(256) void k_compose(const float* __restrict__ emb,
                                                 const float* __restrict__ cw,
                                                 f16* __restrict__ WH,
                                                 f16* __restrict__ WL) {
  int idx = blockIdx.x * 256 + threadIdx.x;        // 512*384 = 196608
  int o = idx / 384, k = idx - o * 384;
  int kk = k >> 7, n = k & 127;
  const float* er = emb + n * 128;
  const float* wr = cw + (size_t)o * 384 + kk;     // stride 3 over e
  float a = 0.f;
  for (int e = 0; e < 128; ++e) a += er[e] * wr[e * 3];
  HL s = splitH(a);
  WH[(size_t)o * 384 + k] = s.h;
  WL[(size_t)o * 384 + k] = s.l;
}

__global__ __launch_bounds__(256) void k_packlin(const float* __restrict__ lw,
                                                 f16* __restrict__ LH,
                                                 f16* __restrict__ LL) {
  int i = blockIdx.x * 256 + threadIdx.x;          // 80*1024 = 81920
  HL s = splitH(lw[i]);
  LH[i] = s.h;
  LL[i] = s.l;
}

// ---- conv as GEMM (split-f16): Y[bt][o] = relu(Xrow(t..t+2) . Wc[o]) -------
__global__ __launch_bounds__(256) void k_conv(const float* __restrict__ x,
                                              const f16* __restrict__ WH,
                                              const f16* __restrict__ WL,
                                              f16* __restrict__ Y) {
  __shared__ f16 XsH[34][136];
  __shared__ f16 XsL[34][136];
  const int tid = threadIdx.x;
  const int b = blockIdx.x >> 6;
  const int t0 = (blockIdx.x & 63) * 32;
  const int n0 = blockIdx.y * 64;
  const int lane = tid & 63, wave = tid >> 6;
  const int n = lane & 15, klo = (lane >> 4) * 8;

  f16x8 bH[12], bL[12];
  {
    const size_t brow = (size_t)(n0 + wave * 16 + n) * 384 + klo;
#pragma unroll
    for (int kt = 0; kt < 12; ++kt) {
      bH[kt] = *(const f16x8*)(WH + brow + kt * 32);
      bL[kt] = *(const f16x8*)(WL + brow + kt * 32);
    }
  }
  for (int idx = tid; idx < 34 * 32; idx += 256) {
    int row = idx >> 5, q = idx & 31;
    int trow = t0 - 1 + row;
    f16x4 vh = {0, 0, 0, 0}, vl = {0, 0, 0, 0};
    if (trow >= 0 && trow < T_) {
      float4 v = *(const float4*)(x + ((size_t)b * T_ + trow) * NS_ + 4 * q);
      HL s0 = splitH(v.x), s1 = splitH(v.y), s2 = splitH(v.z), s3 = splitH(v.w);
      vh[0] = s0.h; vl[0] = s0.l;
      vh[1] = s1.h; vl[1] = s1.l;
      vh[2] = s2.h; vl[2] = s2.l;
      vh[3] = s3.h; vl[3] = s3.l;
    }
    *(f16x4*)&XsH[row][4 * q] = vh;
    *(f16x4*)&XsL[row][4 * q] = vl;
  }
  __syncthreads();

  f32x4 aH_[2] = {{0,0,0,0},{0,0,0,0}}, aM_[2] = {{0,0,0,0},{0,0,0,0}};
#pragma unroll
  for (int kt = 0; kt < 12; ++kt) {
    int kk = kt >> 2, i = (kt & 3) * 32 + klo;
#pragma unroll
    for (int m = 0; m < 2; ++m) {
      f16x8 ah = *(const f16x8*)&XsH[m * 16 + n + kk][i];
      f16x8 al = *(const f16x8*)&XsL[m * 16 + n + kk][i];
      aH_[m] = __builtin_amdgcn_mfma_f32_16x16x32_f16(ah, bH[kt], aH_[m], 0, 0, 0);
      aM_[m] = __builtin_amdgcn_mfma_f32_16x16x32_f16(ah, bL[kt], aM_[m], 0, 0, 0);
      aM_[m] = __builtin_amdgcn_mfma_f32_16x16x32_f16(al, bH[kt], aM_[m], 0, 0, 0);
    }
  }
  const int rq = (lane >> 4) * 4;
#pragma unroll
  for (int m = 0; m < 2; ++m)
#pragma unroll
    for (int q = 0; q < 4; ++q) {
      int rowg = blockIdx.x * 32 + m * 16 + rq + q;
      float v = aH_[m][q] + aM_[m][q];
      Y[(size_t)rowg * CD_ + n0 + wave * 16 + n] = (f16)(v > 0.f ? v : 0.f);
    }
}

// ---------------- BN stats / scale / apply ---------------------------------
__global__ __launch_bounds__(256) void k_bnstats(const f16* __restrict__ Y,
                                                 float* __restrict__ sums,
                                                 float* __restrict__ sumsq) {
  const u32* Y32 = (const u32*)Y;
  int r0 = blockIdx.x * 64;
  float a0 = 0, a1 = 0, q0 = 0, q1 = 0;
  for (int i = 0; i < 64; ++i) {
    u32 v = Y32[(size_t)(r0 + i) * 256 + threadIdx.x];
    float x0 = h2f_lo(v), x1 = h2f_hi(v);
    a0 += x0; a1 += x1; q0 += x0 * x0; q1 += x1 * x1;
  }
  int c = threadIdx.x * 2;
  atomicAdd(&sums[c], a0); atomicAdd(&sums[c + 1], a1);
  atomicAdd(&sumsq[c], q0); atomicAdd(&sumsq[c + 1], q1);
}

__global__ void k_bnscale(const float* __restrict__ sums, const float* __restrict__ sumsq,
                          const float* __restrict__ g, const float* __restrict__ be,
                          float* __restrict__ scl, float* __restrict__ shf) {
  int c = blockIdx.x * 256 + threadIdx.x;
  if (c < CD_) {
    float m = sums[c] * (1.f / 65536.f);
    float v = sumsq[c] * (1.f / 65536.f) - m * m;
    float s = g[c] * rsqrtf(v + 1e-5f);
    scl[c] = s; shf[c] = be[c] - m * s;
  }
}

__global__ __launch_bounds__(256) void k_bnapply(f16* __restrict__ Y,
                                                 const float* __restrict__ scl,
                                                 const float* __restrict__ shf) {
  const int total = BT_ * CD_ / 8;
  int idx0 = blockIdx.x * 256 + threadIdx.x;
  int c0 = (idx0 & 63) * 8;
  float sc[8], sh[8];
#pragma unroll
  for (int j = 0; j < 8; ++j) { sc[j] = scl[c0 + j]; sh[j] = shf[c0 + j]; }
  u32v4* Yv = (u32v4*)Y;
  for (int idx = idx0; idx < total; idx += 2048 * 256) {
    u32v4 v = Yv[idx], o;
#pragma unroll
    for (int j = 0; j < 4; ++j) {
      float lo = h2f_lo(v[j]) * sc[2 * j] + sh[2 * j];
      float hi = h2f_hi(v[j]) * sc[2 * j + 1] + sh[2 * j + 1];
      o[j] = pack2h(lo, hi);
    }
    Yv[idx] = o;
  }
}

// ---------------- persistent bidirectional LSTM (K-split waves) -------------
// 128 blocks x 256 thr, 4 groups (dir x batch-half) of 32 blocks; block owns
// 16 units. Wave = K-quarter (128 units), all 4 gates over its slice; each
// wave polls only its own slice (8 producer blocks), decodes in registers,
// feeds MFMA directly. Parity-double-buffered partial LDS -> ONE barrier/step.
// h published as bits(f16)+1 into zeroed T-deep slots via relaxed agent
// stores (sc1, L2-bypass); ALL hT readers (here and k_final) use the same
// agent-scope loads so no stale-XCD-L2 line can ever be observed.
// NOTE (R13/R14 lesson): the loop-end x prefetch + IH-before-poll order is a
// measured local optimum — IH's load-wait hides inside the poll wait; any
// reordering of the prefetch regressed.
__global__ __launch_bounds__(256, 1) void k_lstm(
    const f16* __restrict__ Y, const float* __restrict__ w_ih_f,
    const float* __restrict__ w_hh_f, const float* __restrict__ b_f,
    const float* __restrict__ w_ih_b, const float* __restrict__ w_hh_b,
    const float* __restrict__ b_b, u16* __restrict__ hT) {
  __shared__ float g_lds[2][4][4][16][17];  // [parity][gate][wave][row][col]
  const int tid = threadIdx.x;
  const int lane = tid & 63, wv = tid >> 6;
  const int bid = blockIdx.x;
  const int g = bid >> 5;                          // group 0..3
  const int dir = g >> 1, bh = g & 1;
  const int u0 = (bid & 31) * 16;                  // hidden-unit base
  const int n = lane & 15;                         // batch row / unit col
  const int klo = (lane >> 4) * 8;
  const int kq = wv * 128 + klo;                   // wave K-slice + lane offset

  const float* Wih = dir ? w_ih_b : w_ih_f;
  const float* Whh = dir ? w_hh_b : w_hh_f;
  const float* bias = dir ? b_b : b_f;

  // weights: per wave, all 4 gates x its K-quarter (4 kt of 32) x split hi/lo
  f16x8 whh_h[4][4], whh_l[4][4], wih_h[4][4], wih_l[4][4];
#pragma unroll
  for (int gt = 0; gt < 4; ++gt) {
    const size_t r = (size_t)(gt * 512 + u0 + n) * 512 + kq;
#pragma unroll
    for (int q = 0; q < 4; ++q) {
      const float* ph = Whh + r + q * 32;
      const float* pi = Wih + r + q * 32;
      f16x8 a, b, c, d;
#pragma unroll
      for (int j = 0; j < 8; ++j) {
        HL s1 = splitH(ph[j]);
        HL s2 = splitH(pi[j]);
        a[j] = s1.h; b[j] = s1.l;
        c[j] = s2.h; d[j] = s2.l;
      }
      whh_h[gt][q] = a; whh_l[gt][q] = b; wih_h[gt][q] = c; wih_l[gt][q] = d;
    }
  }
#pragma unroll
  for (int gt = 0; gt < 4; ++gt)
#pragma unroll
    for (int q = 0; q < 4; ++q)
      asm volatile("" : "+v"(whh_h[gt][q]), "+v"(whh_l[gt][q]),
                        "+v"(wih_h[gt][q]), "+v"(wih_l[gt][q]));

  const int bb = tid >> 4, uu = tid & 15;          // gate-math cell
  const float bi = bias[u0 + uu];
  const float bf = bias[512 + u0 + uu];
  const float bg = bias[1024 + u0 + uu];
  const float bo = bias[1536 + u0 + uu];
  float c_st = 0.f;

  const size_t gslot = (size_t)g * T_;
  const size_t yrow = (size_t)(bh * 16 + n) * T_;
  const int rq = (lane >> 4) * 4;

  // ---- prologue: load x-fragments for step 0 (wave's quarter only) --------
  f16x8 xf0, xf1, xf2, xf3;
  {
    const int t0 = dir ? (T_ - 1) : 0;
    const f16* xb = Y + (yrow + t0) * 512 + kq;
    xf0 = *(const f16x8*)(xb);
    xf1 = *(const f16x8*)(xb + 32);
    xf2 = *(const f16x8*)(xb + 64);
    xf3 = *(const f16x8*)(xb + 96);
  }

  for (int s = 0; s < T_; ++s) {
    const int par = s & 1;
    f32x4 a0 = {0,0,0,0}, a1 = {0,0,0,0}, a2 = {0,0,0,0}, a3 = {0,0,0,0};

    // ---- poll own K-slice of h(s-1); decoded registers feed MFMA directly -
    if (s > 0) {
      const u16* hrow = hT + ((gslot + (s - 1)) * 16 + n) * 512 + kq;
      u32v4 dec[4];
      for (;;) {
        u32 bad = 0;
#pragma unroll
        for (int q = 0; q < 4; ++q) {
          const u64* p = (const u64*)(hrow + q * 32);
          u64 a = __hip_atomic_load(p, __ATOMIC_RELAXED, __HIP_MEMORY_SCOPE_AGENT);
          u64 b = __hip_atomic_load(p + 1, __ATOMIC_RELAXED, __HIP_MEMORY_SCOPE_AGENT);
          u32 w0 = (u32)a, w1 = (u32)(a >> 32), w2 = (u32)b, w3 = (u32)(b >> 32);
          u32 d0 = w0 - 0x00010001u, d1 = w1 - 0x00010001u;
          u32 d2 = w2 - 0x00010001u, d3 = w3 - 0x00010001u;
          bad |= (d0 & ~w0 & 0x80008000u) | (d1 & ~w1 & 0x80008000u) |
                 (d2 & ~w2 & 0x80008000u) | (d3 & ~w3 & 0x80008000u);
          dec[q][0] = d0; dec[q][1] = d1; dec[q][2] = d2; dec[q][3] = d3;
        }
        if (!__any(bad)) break;
      }
      // HH MFMA: 4 gates x 4 kt x split, A = decoded h fragments
#pragma unroll
      for (int q = 0; q < 4; ++q) {
        f16x8 hf = __builtin_bit_cast(f16x8, dec[q]);
        a0 = __builtin_amdgcn_mfma_f32_16x16x32_f16(hf, whh_h[0][q], a0, 0, 0, 0);
        a0 = __builtin_amdgcn_mfma_f32_16x16x32_f16(hf, whh_l[0][q], a0, 0, 0, 0);
        a1 = __builtin_amdgcn_mfma_f32_16x16x32_f16(hf, whh_h[1][q], a1, 0, 0, 0);
        a1 = __builtin_amdgcn_mfma_f32_16x16x32_f16(hf, whh_l[1][q], a1, 0, 0, 0);
        a2 = __builtin_amdgcn_mfma_f32_16x16x32_f16(hf, whh_h[2][q], a2, 0, 0, 0);
        a2 = __builtin_amdgcn_mfma_f32_16x16x32_f16(hf, whh_l[2][q], a2, 0, 0, 0);
        a3 = __builtin_amdgcn_mfma_f32_16x16x32_f16(hf, whh_h[3][q], a3, 0, 0, 0);
        a3 = __builtin_amdgcn_mfma_f32_16x16x32_f16(hf, whh_l[3][q], a3, 0, 0, 0);
      }
    }

    // ---- IH MFMA from prefetched x fragments ------------------------------
    {
      f16x8 xq[4] = {xf0, xf1, xf2, xf3};
#pragma unroll
      for (int q = 0; q < 4; ++q) {
        a0 = __builtin_amdgcn_mfma_f32_16x16x32_f16(xq[q], wih_h[0][q], a0, 0, 0, 0);
        a0 = __builtin_amdgcn_mfma_f32_16x16x32_f16(xq[q], wih_l[0][q], a0, 0, 0, 0);
        a1 = __builtin_amdgcn_mfma_f32_16x16x32_f16(xq[q], wih_h[1][q], a1, 0, 0, 0);
        a1 = __builtin_amdgcn_mfma_f32_16x16x32_f16(xq[q], wih_l[1][q], a1, 0, 0, 0);
        a2 = __builtin_amdgcn_mfma_f32_16x16x32_f16(xq[q], wih_h[2][q], a2, 0, 0, 0);
        a2 = __builtin_amdgcn_mfma_f32_16x16x32_f16(xq[q], wih_l[2][q], a2, 0, 0, 0);
        a3 = __builtin_amdgcn_mfma_f32_16x16x32_f16(xq[q], wih_h[3][q], a3, 0, 0, 0);
        a3 = __builtin_amdgcn_mfma_f32_16x16x32_f16(xq[q], wih_l[3][q], a3, 0, 0, 0);
      }
    }

    // ---- write per-wave partials, single barrier ---------------------------
#pragma unroll
    for (int q = 0; q < 4; ++q) {
      g_lds[par][0][wv][rq + q][n] = a0[q];
      g_lds[par][1][wv][rq + q][n] = a1[q];
      g_lds[par][2][wv][rq + q][n] = a2[q];
      g_lds[par][3][wv][rq + q][n] = a3[q];
    }
    __syncthreads();

    // ---- gate math: sum 4 wave-partials per gate, update c, publish --------
    {
      float gi = g_lds[par][0][0][bb][uu] + g_lds[par][0][1][bb][uu] +
                 g_lds[par][0][2][bb][uu] + g_lds[par][0][3][bb][uu] + bi;
      float gf = g_lds[par][1][0][bb][uu] + g_lds[par][1][1][bb][uu] +
                 g_lds[par][1][2][bb][uu] + g_lds[par][1][3][bb][uu] + bf;
      float gg = g_lds[par][2][0][bb][uu] + g_lds[par][2][1][bb][uu] +
                 g_lds[par][2][2][bb][uu] + g_lds[par][2][3][bb][uu] + bg;
      float go = g_lds[par][3][0][bb][uu] + g_lds[par][3][1][bb][uu] +
                 g_lds[par][3][2][bb][uu] + g_lds[par][3][3][bb][uu] + bo;
      c_st = sigm(gf) * c_st + sigm(gi) * tanh_(gg);
      f16 h16 = (f16)(sigm(go) * tanh_(c_st));
      u32 enc = (u32)(u16)(__builtin_bit_cast(u16, h16) + 1);
      u32 o1 = (u32)__shfl_xor((int)enc, 1);
      u32 p2 = (uu & 1) ? (o1 | (enc << 16)) : (enc | (o1 << 16));
      u32 o2 = (u32)__shfl_xor((int)p2, 2);
      u64 q64 = (uu & 2) ? ((u64)o2 | ((u64)p2 << 32))
                         : ((u64)p2 | ((u64)o2 << 32));
      if ((uu & 3) == 0) {
        u64* dst = (u64*)(hT + ((gslot + s) * 16 + bb) * 512 + u0 + uu);
        __hip_atomic_store(dst, q64, __ATOMIC_RELAXED, __HIP_MEMORY_SCOPE_AGENT);
      }
    }

    // ---- prefetch x(s+1) for wave's quarter (covered by next poll) ---------
    if (s + 1 < T_) {
      const int t1 = dir ? (T_ - 2 - s) : (s + 1);
      const f16* xb = Y + (yrow + t1) * 512 + kq;
      xf0 = *(const f16x8*)(xb);
      xf1 = *(const f16x8*)(xb + 32);
      xf2 = *(const f16x8*)(xb + 64);
      xf3 = *(const f16x8*)(xb + 96);
    }
  }
}

// ---------------- final linear: out = decode(hT) @ lin_w^T + lin_b ----------
// hT is written with agent-scope (L2-bypassing) stores in k_lstm, so it MUST
// be read with agent-scope loads here too: plain loads can hit stale XCD-L2
// lines (harness 0xAA poison / memset zeros) that sc1 stores never update.
__global__ __launch_bounds__(256) void k_final(const u16* __restrict__ hT,
                                               const f16* __restrict__ LH,
                                               const f16* __restrict__ LL,
                                               const float* __restrict__ lin_b,
                                               float* __restrict__ out) {
  __shared__ f16 As[64][40];
  __shared__ f16 BsH[80][40];
  __shared__ f16 BsL[80][40];
  const int tid = threadIdx.x;
  const int bt0 = blockIdx.x * 64;
  const int b = bt0 >> 11;                 // batch
  const int bh = b >> 4, bi = b & 15;
  const int lane = tid & 63, wave = tid >> 6;
  const int n = lane & 15, klo = (lane >> 4) * 8;
  f32x4 acc[5] = {{0,0,0,0},{0,0,0,0},{0,0,0,0},{0,0,0,0},{0,0,0,0}};
  float bl[5];
#pragma unroll
  for (int nt = 0; nt < 5; ++nt) bl[nt] = lin_b[nt * 16 + n];
  const int ar = tid >> 2, aoff = (tid & 3) * 8;
  const int tr = (bt0 & 2047) + ar;
  for (int kt = 0; kt < 32; ++kt) {
    __syncthreads();
    {
      size_t src;
      if (kt < 16)
        src = ((size_t)(bh * T_ + tr) * 16 + bi) * 512 + kt * 32 + aoff;
      else
        src = ((size_t)((2 + bh) * T_ + (T_ - 1 - tr)) * 16 + bi) * 512 +
              (kt - 16) * 32 + aoff;
      const u64* p = (const u64*)(hT + src);
      u64 a = __hip_atomic_load(p, __ATOMIC_RELAXED, __HIP_MEMORY_SCOPE_AGENT);
      u64 b2 = __hip_atomic_load(p + 1, __ATOMIC_RELAXED, __HIP_MEMORY_SCOPE_AGENT);
      u32v4 v;
      v[0] = (u32)a; v[1] = (u32)(a >> 32);
      v[2] = (u32)b2; v[3] = (u32)(b2 >> 32);
#pragma unroll
      for (int j = 0; j < 4; ++j) v[j] -= 0x00010001u;
      *(u32v4*)&As[ar][aoff] = v;
    }
    {
      int row = tid >> 2, off = (tid & 3) * 8;
      *(u32v4*)&BsH[row][off] = *(const u32v4*)(LH + (size_t)row * 1024 + kt * 32 + off);
      *(u32v4*)&BsL[row][off] = *(const u32v4*)(LL + (size_t)row * 1024 + kt * 32 + off);
      if (tid < 64) {
        int c2 = 256 + tid, row2 = c2 >> 2, off2 = (c2 & 3) * 8;
        *(u32v4*)&BsH[row2][off2] = *(const u32v4*)(LH + (size_t)row2 * 1024 + kt * 32 + off2);
        *(u32v4*)&BsL[row2][off2] = *(const u32v4*)(LL + (size_t)row2 * 1024 + kt * 32 + off2);
      }
    }
    __syncthreads();
    f16x8 af = *(const f16x8*)&As[wave * 16 + n][klo];
#pragma unroll
    for (int nt = 0; nt < 5; ++nt) {
      f16x8 bh_ = *(const f16x8*)&BsH[nt * 16 + n][klo];
      f16x8 bl_ = *(const f16x8*)&BsL[nt * 16 + n][klo];
      acc[nt] = __builtin_amdgcn_mfma_f32_16x16x32_f16(af, bh_, acc[nt], 0, 0, 0);
      acc[nt] = __builtin_amdgcn_mfma_f32_16x16x32_f16(af, bl_, acc[nt], 0, 0, 0);
    }
  }
  const int rq = (lane >> 4) * 4;
#pragma unroll
  for (int nt = 0; nt < 5; ++nt)
#pragma unroll
    for (int q = 0; q < 4; ++q)
      out[(size_t)(bt0 + wave * 16 + rq + q) * NM_ + nt * 16 + n] = acc[nt][q] + bl[nt];
}

// ---------------- launcher ---------------------------------------------------
extern "C" void kernel_launch(void* const* d_in, const int* in_sizes, int n_in,
                              void* d_out, int out_size, void* d_ws, size_t ws_size,
                              hipStream_t stream) {
  const float* x_in   = (const float*)d_in[0];
  const float* emb    = (const float*)d_in[1];
  const float* conv_w = (const float*)d_in[2];
  const float* bn_g   = (const float*)d_in[3];
  const float* bn_b   = (const float*)d_in[4];
  const float* w_ih_f = (const float*)d_in[5];
  const float* w_hh_f = (const float*)d_in[6];
  const float* b_f    = (const float*)d_in[7];
  const float* w_ih_b = (const float*)d_in[8];
  const float* w_hh_b = (const float*)d_in[9];
  const float* b_b    = (const float*)d_in[10];
  const float* lin_w  = (const float*)d_in[11];
  const float* lin_b  = (const float*)d_in[12];
  float* out = (float*)d_out;

  char* ws = (char*)d_ws;
  size_t o = 0;
  auto alloc = [&](size_t bytes) {
    void* p = ws + o;
    o = (o + bytes + 255) & ~(size_t)255;
    return p;
  };
  f16* WcH  = (f16*)alloc(512 * 384 * 2);
  f16* WcL  = (f16*)alloc(512 * 384 * 2);
  f16* LinH = (f16*)alloc(80 * 1024 * 2);
  f16* LinL = (f16*)alloc(80 * 1024 * 2);
  f16* Y    = (f16*)alloc((size_t)BT_ * CD_ * 2);          // 64 MiB
  u16* hT   = (u16*)alloc((size_t)4 * T_ * 16 * 512 * 2);  // 128 MiB
  float* sums  = (float*)alloc(512 * 4);
  float* sumsq = (float*)alloc(512 * 4);
  float* scl   = (float*)alloc(512 * 4);
  float* shf   = (float*)alloc(512 * 4);
  if (o > ws_size) return;  // workspace too small -> loud failure

  (void)hipMemsetAsync(sums, 0, 512 * 4, stream);
  (void)hipMemsetAsync(sumsq, 0, 512 * 4, stream);
  (void)hipMemsetAsync(hT, 0, (size_t)4 * T_ * 16 * 512 * 2, stream);

  k_compose<<<768, 256, 0, stream>>>(emb, conv_w, WcH, WcL);
  k_packlin<<<320, 256, 0, stream>>>(lin_w, LinH, LinL);
  k_conv<<<dim3(2048, 8), 256, 0, stream>>>(x_in, WcH, WcL, Y);
  k_bnstats<<<1024, 256, 0, stream>>>(Y, sums, sumsq);
  k_bnscale<<<2, 256, 0, stream>>>(sums, sumsq, bn_g, bn_b, scl, shf);
  k_bnapply<<<2048, 256, 0, stream>>>(Y, scl, shf);

  // plain launch: no grid-sync API used; 128 blocks @ 1 block/CU are
  // trivially co-resident on 256 CUs.
  k_lstm<<<128, 256, 0, stream>>>(Y, w_ih_f, w_hh_f, b_f, w_ih_b, w_hh_b,
                                  b_b, hT);
  k_final<<<1024, 256, 0, stream>>>(hT, LinH, LinL, lin_b, out);
}